// Round 1
// baseline (974.034 us; speedup 1.0000x reference)
//
#include <hip/hip_runtime.h>
#include <math.h>
#include <stdint.h>

#define MAXI 8
#define MAXSEG (2*MAXI+2)
#define VISBIT (1<<30)

typedef __attribute__((ext_vector_type(8))) short short8;
typedef __attribute__((ext_vector_type(4))) float f32x4;

static __device__ __forceinline__ unsigned short f2bf(float f) {
  union { float f; unsigned int u; } v; v.f = f;
  unsigned int x = v.u;
  unsigned int r = (x + 0x7FFFu + ((x >> 16) & 1u)) >> 16;
  return (unsigned short)r;
}

static __device__ __forceinline__ void gload_lds16(const void* g, void* lds) {
  __builtin_amdgcn_global_load_lds((const __attribute__((address_space(1))) void*)g,
                                   (__attribute__((address_space(3))) void*)lds, 16, 0, 0);
}

// ---------------- plan: per-sample segment construction ----------------
__global__ void plan_kernel(const int* __restrict__ texts, const int* __restrict__ imgtok_p,
                            int S, int n_visual, int L,
                            int* __restrict__ seg, int* __restrict__ nsegA, int* __restrict__ lenA,
                            int* __restrict__ perA, int* __restrict__ nimgA, int* __restrict__ ostA)
{
  int b = blockIdx.x;
  __shared__ int spos[256];
  __shared__ int scnt;
  if (threadIdx.x == 0) scnt = 0;
  __syncthreads();
  int tok = imgtok_p[0];
  for (int s = threadIdx.x; s < S; s += blockDim.x) {
    if (texts[(size_t)b*S + s] == tok) {
      int i = atomicAdd(&scnt, 1);
      if (i < 256) spos[i] = s;
    }
  }
  __syncthreads();
  if (threadIdx.x != 0) return;
  int n = scnt; if (n > MAXI) n = MAXI;
  // insertion sort
  for (int i = 1; i < n; i++) {
    int key = spos[i]; int j = i - 1;
    while (j >= 0 && spos[j] > key) { spos[j+1] = spos[j]; j--; }
    spos[j+1] = key;
  }
  int* sg = seg + b*MAXSEG*4;
  int ns = 0, o = 0, c = 0, per = 1;
  if (n == 0) {
    sg[0] = 0; sg[1] = 0; sg[2] = S; sg[3] = 0; ns = 1; o = S;
  } else {
    per = n_visual / n;
    int tcs[MAXI+1], tce[MAXI+1]; int ntc = 0; int start = 0;
    for (int i = 0; i < n; i++) {
      int p = spos[i];
      if (p > start) { tcs[ntc] = start; tce[ntc] = p; ntc++; }
      start = p + 1;
    }
    if (start < S) { tcs[ntc] = start; tce[ntc] = S; ntc++; }
    for (int i = 0; i < n; i++) {
      if (i < ntc) {
        sg[ns*4+0] = o; sg[ns*4+1] = tcs[i]; sg[ns*4+2] = tce[i]-tcs[i]; sg[ns*4+3] = (c<<1);
        o += tce[i]-tcs[i]; c++; ns++;
      }
      ostA[b*MAXI + i] = o;
      sg[ns*4+0] = o; sg[ns*4+1] = i*per; sg[ns*4+2] = per; sg[ns*4+3] = (c<<1)|1;
      o += per; c++; ns++;
    }
    if (n < ntc) {
      sg[ns*4+0] = o; sg[ns*4+1] = tcs[ntc-1]; sg[ns*4+2] = tce[ntc-1]-tcs[ntc-1]; sg[ns*4+3] = (c<<1);
      o += sg[ns*4+2]; ns++;
    }
  }
  nsegA[b] = ns; lenA[b] = o; perA[b] = per; nimgA[b] = n;
  for (int i = n; i < MAXI; i++) ostA[b*MAXI + i] = 0;
  for (int t = ns; t < MAXSEG; t++) { sg[t*4+0]=0; sg[t*4+1]=0; sg[t*4+2]=0; sg[t*4+3]=0; }
}

// ---------------- fill per-position src / cid-vis arrays ----------------
__global__ void fill_kernel(const int* __restrict__ texts, int S, int L, int bpb,
                            const int* __restrict__ seg, const int* __restrict__ nsegA,
                            int* __restrict__ srcA, int* __restrict__ cidvA)
{
  int b = blockIdx.x / bpb;
  int j = (blockIdx.x % bpb) * blockDim.x + threadIdx.x;
  if (j >= L) return;
  int ns = nsegA[b];
  const int* sg = seg + b*MAXSEG*4;
  int src = -1, cv = -1;
  for (int t = 0; t < ns; t++) {
    int o = sg[t*4+0], ss = sg[t*4+1], ln = sg[t*4+2], cvis = sg[t*4+3];
    if (j >= o && j < o + ln) {
      if (cvis & 1) src = VISBIT | (ss + (j - o));
      else          src = texts[(size_t)b*S + ss + (j - o)];
      cv = cvis;
    }
  }
  srcA[(size_t)b*L + j] = src;
  cidvA[(size_t)b*L + j] = cv;
}

// ---------------- W_proj -> bf16 transposed [D][DV] ----------------
__global__ void wt_kernel(const float* __restrict__ W, unsigned short* __restrict__ Wt, int D, int DV)
{
  __shared__ float t[32][33];
  int k0 = blockIdx.x*32, n0 = blockIdx.y*32;
  int tx = threadIdx.x, ty = threadIdx.y; // 32 x 8
  for (int i = 0; i < 4; i++) {
    int k = k0 + ty + i*8, nn = n0 + tx;
    t[ty+i*8][tx] = (k < DV && nn < D) ? W[(size_t)k*D + nn] : 0.f;
  }
  __syncthreads();
  for (int i = 0; i < 4; i++) {
    int nn = n0 + ty + i*8, k = k0 + tx;
    if (nn < D && k < DV) Wt[(size_t)nn*DV + k] = f2bf(t[tx][ty+i*8]);
  }
}

// ---------------- text rows + padding rows of fused ----------------
__global__ void gather_kernel(const float* __restrict__ emb, const int* __restrict__ srcA,
                              float* __restrict__ out, int L, int D)
{
  int bid = blockIdx.x;
  int b = bid / L, j = bid % L;
  int s = srcA[(size_t)b*L + j];
  if (s >= 0 && (s & VISBIT)) return; // visual rows written by gemm
  float* orow = out + ((size_t)b*L + j)*(size_t)D;
  if (s < 0) {
    for (int d = threadIdx.x*4; d < D; d += blockDim.x*4)
      *(float4*)&orow[d] = make_float4(0.f,0.f,0.f,0.f);
  } else {
    const float* erow = emb + (size_t)s*D;
    for (int d = threadIdx.x*4; d < D; d += blockDim.x*4)
      *(float4*)&orow[d] = *(const float4*)&erow[d];
  }
}

// ---------------- visual projection GEMM, scatter into fused ----------------
__launch_bounds__(256)
__global__ void gemm_kernel(const float* __restrict__ vis, const unsigned short* __restrict__ Wt,
                            const float* __restrict__ bproj, float* __restrict__ out,
                            const int* __restrict__ perA, const int* __restrict__ nimgA,
                            const int* __restrict__ ostA,
                            int Nv, int DV, int D, int L, int Mt, int Nt)
{
  __shared__ unsigned short As[128*32];
  __shared__ unsigned short Bs[128*32];
  int bid = blockIdx.x;
  int nt = bid % Nt; int mt = (bid/Nt) % Mt; int b = bid/(Nt*Mt);
  int r0 = mt*128, n0 = nt*128;
  int tid = threadIdx.x; int wv = tid>>6, l = tid&63;
  int wm = wv>>1, wn = wv&1;
  f32x4 acc[4][4];
  for (int m=0;m<4;m++) for (int n=0;n<4;n++) acc[m][n] = (f32x4){0.f,0.f,0.f,0.f};

  int nk = DV/32;
  int lr = l & 15, lk = (l>>4)*8;
  for (int kt = 0; kt < nk; ++kt) {
    int k0 = kt*32;
    // stage B (bf16, [128 n][32 k] linear) via global_load_lds
    for (int q = 0; q < 2; q++) {
      int flat = q*256 + tid;
      int row = flat >> 2, sub = flat & 3;
      const unsigned short* g = Wt + (size_t)(n0+row)*DV + k0 + sub*8;
      gload_lds16(g, (char*)Bs + (size_t)flat*16);
    }
    // stage A (fp32 -> bf16, [128 m][32 k] linear) via registers
    for (int q = 0; q < 4; q++) {
      int flat = q*256 + tid;
      int row = flat >> 3, ko = (flat & 7)*4;
      int rr = r0 + row; if (rr >= Nv) rr = Nv - 1;
      const float4 v = *(const float4*)(vis + ((size_t)b*Nv + rr)*DV + k0 + ko);
      ushort4 w; w.x = f2bf(v.x); w.y = f2bf(v.y); w.z = f2bf(v.z); w.w = f2bf(v.w);
      *(ushort4*)&As[row*32 + ko] = w;
    }
    __syncthreads();
    short8 av[4], bv[4];
    for (int m = 0; m < 4; m++) av[m] = *(const short8*)&As[(wm*64 + m*16 + lr)*32 + lk];
    for (int n = 0; n < 4; n++) bv[n] = *(const short8*)&Bs[(wn*64 + n*16 + lr)*32 + lk];
    for (int m = 0; m < 4; m++)
      for (int n = 0; n < 4; n++)
        acc[m][n] = __builtin_amdgcn_mfma_f32_16x16x32_bf16(av[m], bv[n], acc[m][n], 0, 0, 0);
    __syncthreads();
  }

  // epilogue: scatter rows to fused positions
  int per = perA[b], nimg = nimgA[b];
  int rmax = nimg * per; if (rmax > Nv) rmax = Nv;
  float bp[4];
  for (int n = 0; n < 4; n++) bp[n] = bproj[n0 + wn*64 + n*16 + lr];
  for (int m = 0; m < 4; m++) {
    for (int rg = 0; rg < 4; rg++) {
      int r = r0 + wm*64 + m*16 + (l>>4)*4 + rg;
      if (r >= rmax) continue;
      int i = r / per, k = r - i*per;
      int j = ostA[b*MAXI + i] + k;
      float* orow = out + ((size_t)b*L + j)*(size_t)D;
      for (int n = 0; n < 4; n++)
        orow[n0 + wn*64 + n*16 + lr] = acc[m][n][rg] + bp[n];
    }
  }
}

// ---------------- mask ----------------
static __device__ __forceinline__ float maskval(int ck, int k, int cidq, int visq, int q) {
  int cidk = ck >> 1;
  bool m = (ck >= 0) && ((cidk < cidq) || ((cidk == cidq) && (visq || (k <= q))));
  return m ? 1.f : 0.f;
}

__global__ void mask_kernel(const int* __restrict__ cidvA, float* __restrict__ mask, int L)
{
  int bid = blockIdx.x;          // = b*L + q
  int b = bid / L, q = bid - b*L;
  const int* crow = cidvA + (size_t)b*L;
  int cq = crow[q];
  float* row = mask + (size_t)bid * (size_t)L;
  bool qvalid = cq >= 0;
  int cidq = cq >> 1, visq = cq & 1;
  if ((L & 3) == 0) {
    for (int k0 = threadIdx.x*4; k0 < L; k0 += blockDim.x*4) {
      float4 o;
      if (!qvalid) {
        o = make_float4(0.f,0.f,0.f,0.f);
      } else {
        int4 ck = *(const int4*)&crow[k0];
        o.x = maskval(ck.x, k0+0, cidq, visq, q);
        o.y = maskval(ck.y, k0+1, cidq, visq, q);
        o.z = maskval(ck.z, k0+2, cidq, visq, q);
        o.w = maskval(ck.w, k0+3, cidq, visq, q);
      }
      *(float4*)&row[k0] = o;
    }
  } else {
    for (int k = threadIdx.x; k < L; k += blockDim.x)
      row[k] = qvalid ? maskval(crow[k], k, cidq, visq, q) : 0.f;
  }
}

extern "C" void kernel_launch(void* const* d_in, const int* in_sizes, int n_in,
                              void* d_out, int out_size, void* d_ws, size_t ws_size,
                              hipStream_t stream)
{
  const float* visf = (const float*)d_in[0];
  const float* emb  = (const float*)d_in[1];
  const float* W    = (const float*)d_in[2];
  const float* bpj  = (const float*)d_in[3];
  const int* texts  = (const int*)d_in[4];
  const int* imgtok = (const int*)d_in[5];

  const int B = 8;                 // per reference constants
  int D  = in_sizes[3];
  int DV = in_sizes[2] / D;
  int S  = in_sizes[4] / B;
  int Nv = in_sizes[0] / (B * DV);

  // out_size = B*(L*D + L*L)  ->  L
  double qq = (double)out_size / (double)B;
  int L = (int)((-(double)D + sqrt((double)D*(double)D + 4.0*qq)) * 0.5 + 0.5);

  float* out   = (float*)d_out;
  float* maskp = out + (size_t)B * (size_t)L * (size_t)D;

  // workspace carve
  char* p = (char*)d_ws;
  int* srcA  = (int*)p; p += (size_t)B*L*4;
  int* cidvA = (int*)p; p += (size_t)B*L*4;
  int* segA  = (int*)p; p += (size_t)B*MAXSEG*4*4;
  int* nsegA = (int*)p; p += B*4;
  int* lenA  = (int*)p; p += B*4;
  int* perA  = (int*)p; p += B*4;
  int* nimgA = (int*)p; p += B*4;
  int* ostA  = (int*)p; p += B*MAXI*4;
  p = (char*)(((uintptr_t)p + 255) & ~(uintptr_t)255);
  unsigned short* Wt = (unsigned short*)p; p += (size_t)D*DV*2;

  plan_kernel<<<B, 256, 0, stream>>>(texts, imgtok, S, Nv, L, segA, nsegA, lenA, perA, nimgA, ostA);
  int bpb = (L + 255) / 256;
  fill_kernel<<<B*bpb, 256, 0, stream>>>(texts, S, L, bpb, segA, nsegA, srcA, cidvA);
  wt_kernel<<<dim3((DV+31)/32, (D+31)/32), dim3(32,8), 0, stream>>>(W, Wt, D, DV);
  gather_kernel<<<B*L, 256, 0, stream>>>(emb, srcA, out, L, D);
  int Mt = (Nv + 127) / 128, Nt = D / 128;
  gemm_kernel<<<B*Mt*Nt, 256, 0, stream>>>(visf, Wt, bpj, out, perA, nimgA, ostA, Nv, DV, D, L, Mt, Nt);
  mask_kernel<<<B*L, 256, 0, stream>>>(cidvA, maskp, L);
}

// Round 2
// 955.618 us; speedup vs baseline: 1.0193x; 1.0193x over previous
//
#include <hip/hip_runtime.h>
#include <math.h>
#include <stdint.h>

#define MAXI 8
#define MAXSEG (2*MAXI+2)
#define VISBIT (1<<30)

typedef __attribute__((ext_vector_type(8))) short short8;
typedef __attribute__((ext_vector_type(4))) float f32x4;

static __device__ __forceinline__ unsigned short f2bf(float f) {
  union { float f; unsigned int u; } v; v.f = f;
  unsigned int x = v.u;
  unsigned int r = (x + 0x7FFFu + ((x >> 16) & 1u)) >> 16;
  return (unsigned short)r;
}

static __device__ __forceinline__ void gload_lds16(const void* g, void* lds) {
  __builtin_amdgcn_global_load_lds((const __attribute__((address_space(1))) void*)g,
                                   (__attribute__((address_space(3))) void*)lds, 16, 0, 0);
}

// ---------------- plan: per-sample segment construction ----------------
__global__ void plan_kernel(const int* __restrict__ texts, const int* __restrict__ imgtok_p,
                            int S, int n_visual, int L,
                            int* __restrict__ seg, int* __restrict__ nsegA, int* __restrict__ lenA,
                            int* __restrict__ perA, int* __restrict__ nimgA, int* __restrict__ ostA)
{
  int b = blockIdx.x;
  __shared__ int spos[256];
  __shared__ int scnt;
  if (threadIdx.x == 0) scnt = 0;
  __syncthreads();
  int tok = imgtok_p[0];
  for (int s = threadIdx.x; s < S; s += blockDim.x) {
    if (texts[(size_t)b*S + s] == tok) {
      int i = atomicAdd(&scnt, 1);
      if (i < 256) spos[i] = s;
    }
  }
  __syncthreads();
  if (threadIdx.x != 0) return;
  int n = scnt; if (n > MAXI) n = MAXI;
  for (int i = 1; i < n; i++) {
    int key = spos[i]; int j = i - 1;
    while (j >= 0 && spos[j] > key) { spos[j+1] = spos[j]; j--; }
    spos[j+1] = key;
  }
  int* sg = seg + b*MAXSEG*4;
  int ns = 0, o = 0, c = 0, per = 1;
  if (n == 0) {
    sg[0] = 0; sg[1] = 0; sg[2] = S; sg[3] = 0; ns = 1; o = S;
  } else {
    per = n_visual / n;
    int tcs[MAXI+1], tce[MAXI+1]; int ntc = 0; int start = 0;
    for (int i = 0; i < n; i++) {
      int p = spos[i];
      if (p > start) { tcs[ntc] = start; tce[ntc] = p; ntc++; }
      start = p + 1;
    }
    if (start < S) { tcs[ntc] = start; tce[ntc] = S; ntc++; }
    for (int i = 0; i < n; i++) {
      if (i < ntc) {
        sg[ns*4+0] = o; sg[ns*4+1] = tcs[i]; sg[ns*4+2] = tce[i]-tcs[i]; sg[ns*4+3] = (c<<1);
        o += tce[i]-tcs[i]; c++; ns++;
      }
      ostA[b*MAXI + i] = o;
      sg[ns*4+0] = o; sg[ns*4+1] = i*per; sg[ns*4+2] = per; sg[ns*4+3] = (c<<1)|1;
      o += per; c++; ns++;
    }
    if (n < ntc) {
      sg[ns*4+0] = o; sg[ns*4+1] = tcs[ntc-1]; sg[ns*4+2] = tce[ntc-1]-tcs[ntc-1]; sg[ns*4+3] = (c<<1);
      o += sg[ns*4+2]; ns++;
    }
  }
  nsegA[b] = ns; lenA[b] = o; perA[b] = per; nimgA[b] = n;
  for (int i = n; i < MAXI; i++) ostA[b*MAXI + i] = 0;
  for (int t = ns; t < MAXSEG; t++) { sg[t*4+0]=0; sg[t*4+1]=0; sg[t*4+2]=0; sg[t*4+3]=0; }
}

// -------- fill: per-position src index + mask prefix cutoff E ----------
// mask row is prefix-ones: text q -> E=q+1 ; visual q -> E=chunk_end.
__global__ void fill_kernel(const int* __restrict__ texts, int S, int L, int bpb,
                            const int* __restrict__ seg, const int* __restrict__ nsegA,
                            int* __restrict__ srcA, int* __restrict__ EiA)
{
  int b = blockIdx.x / bpb;
  int j = (blockIdx.x % bpb) * blockDim.x + threadIdx.x;
  if (j >= L) return;
  int ns = nsegA[b];
  const int* sg = seg + b*MAXSEG*4;
  int src = -1, E = 0;
  for (int t = 0; t < ns; t++) {
    int o = sg[t*4+0], ss = sg[t*4+1], ln = sg[t*4+2], cvis = sg[t*4+3];
    if (j >= o && j < o + ln) {
      if (cvis & 1) { src = VISBIT | (ss + (j - o)); E = o + ln; }
      else          { src = texts[(size_t)b*S + ss + (j - o)]; E = j + 1; }
    }
  }
  srcA[(size_t)b*L + j] = src;
  EiA[(size_t)b*L + j] = E;
}

// ---------------- W_proj -> bf16 transposed [D][DV] ----------------
__global__ void wt_kernel(const float* __restrict__ W, unsigned short* __restrict__ Wt, int D, int DV)
{
  __shared__ float t[32][33];
  int k0 = blockIdx.x*32, n0 = blockIdx.y*32;
  int tx = threadIdx.x, ty = threadIdx.y; // 32 x 8
  for (int i = 0; i < 4; i++) {
    int k = k0 + ty + i*8, nn = n0 + tx;
    t[ty+i*8][tx] = (k < DV && nn < D) ? W[(size_t)k*D + nn] : 0.f;
  }
  __syncthreads();
  for (int i = 0; i < 4; i++) {
    int nn = n0 + ty + i*8, k = k0 + tx;
    if (nn < D && k < DV) Wt[(size_t)nn*DV + k] = f2bf(t[tx][ty+i*8]);
  }
}

// ---------------- vis fp32 -> bf16 (flat) ----------------
__global__ void viscast_kernel(const float* __restrict__ vis, unsigned short* __restrict__ visb, size_t n)
{
  size_t i = ((size_t)blockIdx.x*blockDim.x + threadIdx.x)*4;
  size_t stride = (size_t)gridDim.x*blockDim.x*4;
  for (; i + 3 < n; i += stride) {
    float4 v = *(const float4*)(vis + i);
    ushort4 w; w.x = f2bf(v.x); w.y = f2bf(v.y); w.z = f2bf(v.z); w.w = f2bf(v.w);
    *(ushort4*)(visb + i) = w;
  }
}

// ---------------- text rows + padding rows of fused ----------------
__global__ void gather_kernel(const float* __restrict__ emb, const int* __restrict__ srcA,
                              float* __restrict__ out, int nrows, int D)
{
  for (int j = blockIdx.x; j < nrows; j += gridDim.x) {
    int s = srcA[j];
    if (s >= 0 && (s & VISBIT)) continue; // visual rows written by gemm
    float* orow = out + (size_t)j*(size_t)D;
    if (s < 0) {
      for (int d = threadIdx.x*4; d < D; d += blockDim.x*4)
        *(float4*)&orow[d] = make_float4(0.f,0.f,0.f,0.f);
    } else {
      const float* erow = emb + (size_t)s*D;
      for (int d = threadIdx.x*4; d < D; d += blockDim.x*4)
        *(float4*)&orow[d] = *(const float4*)&erow[d];
    }
  }
}

// -------- visual projection GEMM (both operands bf16 via global_load_lds) --------
__launch_bounds__(256)
__global__ void gemm_kernel(const unsigned short* __restrict__ visb, const unsigned short* __restrict__ Wt,
                            const float* __restrict__ bproj, float* __restrict__ out,
                            const int* __restrict__ perA, const int* __restrict__ nimgA,
                            const int* __restrict__ ostA,
                            int Nv, int DV, int D, int L, int Mt, int Nt)
{
  __shared__ unsigned short As[128*32];
  __shared__ unsigned short Bs[128*32];
  int nwg = Mt*Nt;
  int hw = blockIdx.x;
  int bid = ((nwg & 7) == 0) ? ((hw & 7)*(nwg>>3) + (hw>>3)) : hw;  // XCD swizzle
  int nt = bid % Nt; int mt = bid / Nt;
  int gr0 = mt*128, n0 = nt*128;
  int tid = threadIdx.x; int wv = tid>>6, l = tid&63;
  int wm = wv>>1, wn = wv&1;
  f32x4 acc[4][4];
  for (int m=0;m<4;m++) for (int n=0;n<4;n++) acc[m][n] = (f32x4){0.f,0.f,0.f,0.f};

  int nk = DV/32;
  int lr = l & 15, lk = (l>>4)*8;
  for (int kt = 0; kt < nk; ++kt) {
    int k0 = kt*32;
    for (int q = 0; q < 2; q++) {
      int flat = q*256 + tid;
      int row = flat >> 2, sub = flat & 3;
      gload_lds16(visb + (size_t)(gr0+row)*DV + k0 + sub*8, (char*)As + (size_t)flat*16);
      gload_lds16(Wt   + (size_t)(n0 +row)*DV + k0 + sub*8, (char*)Bs + (size_t)flat*16);
    }
    __syncthreads();
    short8 av[4], bv[4];
    for (int m = 0; m < 4; m++) av[m] = *(const short8*)&As[(wm*64 + m*16 + lr)*32 + lk];
    for (int n = 0; n < 4; n++) bv[n] = *(const short8*)&Bs[(wn*64 + n*16 + lr)*32 + lk];
    for (int m = 0; m < 4; m++)
      for (int n = 0; n < 4; n++)
        acc[m][n] = __builtin_amdgcn_mfma_f32_16x16x32_bf16(av[m], bv[n], acc[m][n], 0, 0, 0);
    __syncthreads();
  }

  // epilogue: scatter rows to fused positions
  float bp[4];
  for (int n = 0; n < 4; n++) bp[n] = bproj[n0 + wn*64 + n*16 + lr];
  for (int m = 0; m < 4; m++) {
    for (int rg = 0; rg < 4; rg++) {
      int grow = gr0 + wm*64 + m*16 + (l>>4)*4 + rg;
      int b = grow / Nv, r = grow - b*Nv;
      int per = perA[b];
      int rmax = nimgA[b] * per; if (rmax > Nv) rmax = Nv;
      if (r >= rmax) continue;
      int i = r / per, k = r - i*per;
      int j = ostA[b*MAXI + i] + k;
      float* orow = out + ((size_t)b*L + j)*(size_t)D;
      for (int n = 0; n < 4; n++)
        orow[n0 + wn*64 + n*16 + lr] = acc[m][n][rg] + bp[n];
    }
  }
}

// ---------------- mask: prefix-ones rows, pure streaming stores ----------------
#define MROWS 4
__global__ void mask_kernel(const int* __restrict__ EiA, float* __restrict__ mask, int L, int nrows)
{
  int g0 = blockIdx.x * MROWS;
  if ((L & 3) == 0) {
    for (int rr = 0; rr < MROWS; rr++) {
      int row = g0 + rr;
      if (row >= nrows) return;
      int E = EiA[row];
      float* rp = mask + (size_t)row * (size_t)L;
      for (int k0 = threadIdx.x*4; k0 < L; k0 += blockDim.x*4) {
        float4 o;
        o.x = (k0+0 < E) ? 1.f : 0.f;
        o.y = (k0+1 < E) ? 1.f : 0.f;
        o.z = (k0+2 < E) ? 1.f : 0.f;
        o.w = (k0+3 < E) ? 1.f : 0.f;
        *(float4*)&rp[k0] = o;
      }
    }
  } else {
    for (int rr = 0; rr < MROWS; rr++) {
      int row = g0 + rr;
      if (row >= nrows) return;
      int E = EiA[row];
      float* rp = mask + (size_t)row * (size_t)L;
      for (int k = threadIdx.x; k < L; k += blockDim.x)
        rp[k] = (k < E) ? 1.f : 0.f;
    }
  }
}

extern "C" void kernel_launch(void* const* d_in, const int* in_sizes, int n_in,
                              void* d_out, int out_size, void* d_ws, size_t ws_size,
                              hipStream_t stream)
{
  const float* visf = (const float*)d_in[0];
  const float* emb  = (const float*)d_in[1];
  const float* W    = (const float*)d_in[2];
  const float* bpj  = (const float*)d_in[3];
  const int* texts  = (const int*)d_in[4];
  const int* imgtok = (const int*)d_in[5];

  const int B = 8;
  int D  = in_sizes[3];
  int DV = in_sizes[2] / D;
  int S  = in_sizes[4] / B;
  int Nv = in_sizes[0] / (B * DV);

  double qq = (double)out_size / (double)B;
  int L = (int)((-(double)D + sqrt((double)D*(double)D + 4.0*qq)) * 0.5 + 0.5);

  float* out   = (float*)d_out;
  float* maskp = out + (size_t)B * (size_t)L * (size_t)D;

  // workspace carve
  char* p = (char*)d_ws;
  int* srcA  = (int*)p; p += (size_t)B*L*4;
  int* EiA   = (int*)p; p += (size_t)B*L*4;
  int* segA  = (int*)p; p += (size_t)B*MAXSEG*4*4;
  int* nsegA = (int*)p; p += B*4;
  int* lenA  = (int*)p; p += B*4;
  int* perA  = (int*)p; p += B*4;
  int* nimgA = (int*)p; p += B*4;
  int* ostA  = (int*)p; p += B*MAXI*4;
  p = (char*)(((uintptr_t)p + 255) & ~(uintptr_t)255);
  unsigned short* Wt = (unsigned short*)p; p += (size_t)D*DV*2;
  p = (char*)(((uintptr_t)p + 255) & ~(uintptr_t)255);
  unsigned short* visb = (unsigned short*)p; p += (size_t)B*Nv*DV*2;

  plan_kernel<<<B, 256, 0, stream>>>(texts, imgtok, S, Nv, L, segA, nsegA, lenA, perA, nimgA, ostA);
  int bpb = (L + 255) / 256;
  fill_kernel<<<B*bpb, 256, 0, stream>>>(texts, S, L, bpb, segA, nsegA, srcA, EiA);
  wt_kernel<<<dim3((DV+31)/32, (D+31)/32), dim3(32,8), 0, stream>>>(W, Wt, D, DV);
  viscast_kernel<<<2048, 256, 0, stream>>>(visf, visb, (size_t)B*Nv*DV);
  gather_kernel<<<2048, 256, 0, stream>>>(emb, srcA, out, B*L, D);
  int Mt = (B*Nv) / 128, Nt = D / 128;   // Nv multiple of 128 here (2304); generic guard below
  if ((B*Nv) % 128 != 0) Mt = (B*Nv + 127)/128; // safety (rows clamped by rmax in epilogue)
  gemm_kernel<<<Mt*Nt, 256, 0, stream>>>(visb, Wt, bpj, out, perA, nimgA, ostA, Nv, DV, D, L, Mt, Nt);
  mask_kernel<<<(B*L + MROWS-1)/MROWS, 256, 0, stream>>>(EiA, maskp, L, B*L);
}